// Round 19
// baseline (235.341 us; speedup 1.0000x reference)
//
#include <hip/hip_runtime.h>

#define VOCAB 32000
#define EMB 32
#define HID 16
#define SEQ 128
#define BATCH 32
#define NROW (SEQ * BATCH)  // 4096 rows

typedef float f32x2 __attribute__((ext_vector_type(2)));
typedef float f32x4 __attribute__((ext_vector_type(4)));

// v_pk_fma_f32 with src0 WORD-BROADCAST via op_sel (strings verified on-device
// in R13): lo = word0 of the h-pair into both halves, hi = word1. h-pair is a
// per-lane VGPR pair ("v"), w-pair is wave-uniform SGPR pair ("s", 1 scalar
// read: legal). This removes the compiler's per-use {h,h} v_mov
// materialization (R18 diagnosis: VGPR=24 < 32 needed for broadcast pairs ->
// ~2x VALU bloat, invariant to occupancy/unroll/SMEM width).
__device__ __forceinline__ void pk_fma_lo(f32x2& acc, f32x2 h2, f32x2 w2) {
    asm("v_pk_fma_f32 %0, %1, %2, %0 op_sel:[0,0,0] op_sel_hi:[0,1,1]"
        : "+v"(acc) : "v"(h2), "s"(w2));
}
__device__ __forceinline__ void pk_fma_hi(f32x2& acc, f32x2 h2, f32x2 w2) {
    asm("v_pk_fma_f32 %0, %1, %2, %0 op_sel:[1,0,0] op_sel_hi:[1,1,1]"
        : "+v"(acc) : "v"(h2), "s"(w2));
}

// ---------------------------------------------------------------------------
// K0: A = X@Wx (parallel, R14 — unchanged).
// ---------------------------------------------------------------------------
__global__ __launch_bounds__(512) void embed_xw(
    const int* __restrict__ idx, const float* __restrict__ lookup,
    const float* __restrict__ Wx, float* __restrict__ A)
{
    __shared__ float sWx[EMB][HID];
    const int tid = threadIdx.x;
    ((float*)sWx)[tid] = Wx[tid];  // 512 == EMB*HID
    __syncthreads();

    const int g = blockIdx.x * 512 + tid;
    const int row = g >> 4, j = g & 15;
    const float* xr = lookup + (size_t)idx[row] * EMB;
    float a0 = 0.f, a1 = 0.f;
    #pragma unroll
    for (int e = 0; e < EMB; e += 2) {
        a0 += xr[e] * sWx[e][j];
        a1 += xr[e + 1] * sWx[e + 1][j];
    }
    A[g] = a0 + a1;
}

// ---------------------------------------------------------------------------
// K1: serial recurrence (R14 — unchanged); no per-step barrier.
// ---------------------------------------------------------------------------
__global__ __launch_bounds__(512) void rnn_recur(
    const float* __restrict__ A, const float* __restrict__ Wh,
    float* __restrict__ Hout)
{
    __shared__ __align__(16) float sH[BATCH][HID];

    const int tid = threadIdx.x;
    const int b = tid >> 4, j = tid & 15;

    float wh[HID];
    #pragma unroll
    for (int k = 0; k < HID; ++k) wh[k] = Wh[k * HID + j];  // column j

    sH[b][j] = 1.0f;  // torch inits H to ones
    __syncthreads();

    float a0r = A[0 * 512 + tid];
    float a1r = A[1 * 512 + tid];
    float a2r = A[2 * 512 + tid];
    float a3r = A[3 * 512 + tid];

#define RNN_STEP(AR, T)                                                     \
    {                                                                       \
        float acc = AR;                                                     \
        if ((T) + 4 < SEQ) AR = A[((T) + 4) * 512 + tid];                   \
        const f32x4* sH4 = (const f32x4*)&sH[b][0];                         \
        f32x4 h0 = sH4[0], h1 = sH4[1], h2v = sH4[2], h3v = sH4[3];         \
        acc += h0.x * wh[0] + h0.y * wh[1] + h0.z * wh[2] + h0.w * wh[3];   \
        acc += h1.x * wh[4] + h1.y * wh[5] + h1.z * wh[6] + h1.w * wh[7];   \
        acc += h2v.x * wh[8] + h2v.y * wh[9] + h2v.z * wh[10]               \
             + h2v.w * wh[11];                                              \
        acc += h3v.x * wh[12] + h3v.y * wh[13] + h3v.z * wh[14]             \
             + h3v.w * wh[15];                                              \
        float e2 = __expf(2.f * acc);   /* tanh = 1 - 2/(e^{2a}+1) */       \
        float h = 1.f - 2.f / (e2 + 1.f);                                   \
        sH[b][j] = h;                                                       \
        Hout[(T) * 512 + tid] = h;                                          \
    }

    for (int t = 0; t < SEQ; t += 4) {
        RNN_STEP(a0r, t + 0)
        RNN_STEP(a1r, t + 1)
        RNN_STEP(a2r, t + 2)
        RNN_STEP(a3r, t + 3)
    }
#undef RNN_STEP
}

// ---------------------------------------------------------------------------
// K2 (v6): sum-of-exp, lane=row, EXACT R14/R16 shape (512 thr, 8 waves,
// 8 col-chunks, __expf) with ONE change: H stored as 8 packed f32x2 pairs
// (16 VGPRs) consumed via op_sel-broadcast pk_fma — no {h,h} pair
// materialization. 500x8=4000 cols/chunk, no tail, no mask.
// ---------------------------------------------------------------------------
#define CSL 500  // cols per wave slice

__global__ __launch_bounds__(512, 4) void sum_exp_partial(
    const float* __restrict__ H, const float* __restrict__ Wo,
    float* __restrict__ P)
{
    __shared__ float part[8][64];

    const int tid = threadIdx.x;
    const int lane = tid & 63;
    const int wave = tid >> 6;                    // 0..7
    const int rgrp = blockIdx.x >> 3;             // 0..63
    const int cchunk = blockIdx.x & 7;            // 0..7
    const int row0 = rgrp * 64;
    const int c0 = __builtin_amdgcn_readfirstlane(cchunk * 4000 + wave * CSL);

    // per-lane H row as 8 PACKED pairs {h2q, h2q+1} (16 VGPRs, fits)
    f32x2 hq[8];
    {
        const f32x2* h2p = (const f32x2*)(H + (size_t)(row0 + lane) * HID);
        #pragma unroll
        for (int q = 0; q < 8; ++q) hq[q] = h2p[q];
    }

    const float* wbase = Wo + c0;
    float acc0 = 0.f, acc1 = 0.f, acc2 = 0.f, acc3 = 0.f;
    for (int v = 0; v < CSL; v += 4) {
        f32x2 a01 = {0.f, 0.f}, a23 = {0.f, 0.f};
        #pragma unroll
        for (int q = 0; q < 8; ++q) {
            // w rows k=2q and k=2q+1, 4 cols each (wave-uniform s_loads)
            f32x4 wa = *(const f32x4*)(wbase + (size_t)(2 * q) * VOCAB + v);
            f32x4 wb = *(const f32x4*)(wbase + (size_t)(2 * q + 1) * VOCAB + v);
            pk_fma_lo(a01, hq[q], wa.xy);   // h_{2q}   * w_{2q}[c0..1]
            pk_fma_lo(a23, hq[q], wa.zw);   // h_{2q}   * w_{2q}[c2..3]
            pk_fma_hi(a01, hq[q], wb.xy);   // h_{2q+1} * w_{2q+1}[c0..1]
            pk_fma_hi(a23, hq[q], wb.zw);   // h_{2q+1} * w_{2q+1}[c2..3]
        }
        acc0 += __expf(a01.x); acc1 += __expf(a01.y);
        acc2 += __expf(a23.x); acc3 += __expf(a23.y);
    }

    part[wave][lane] = (acc0 + acc1) + (acc2 + acc3);
    __syncthreads();
    if (wave == 0) {
        float tot = 0.f;
        #pragma unroll
        for (int w = 0; w < 8; ++w) tot += part[w][lane];
        P[(size_t)cchunk * NROW + row0 + lane] = tot;  // written exactly once
    }
}

// ---------------------------------------------------------------------------
// K3: output pass — EXACT R14 structure (measured 107us: NT plateau; R15
// plain/blocked and R18 RV=32 all no better). logS fused from 8 partials.
// ---------------------------------------------------------------------------
#define RV 64     // rows per block
#define VSK 2048  // vocab cols per block slice

__global__ __launch_bounds__(512, 4) void write_logits(
    const float* __restrict__ H, const float* __restrict__ Wo,
    const float* __restrict__ P, float* __restrict__ out)
{
    __shared__ __align__(16) float sH[RV * HID];  // 4 KB
    __shared__ __align__(16) float sLogS[RV];

    const int tid = threadIdx.x;
    const int vtile = blockIdx.x & 15;
    const int row0 = (blockIdx.x >> 4) * RV;

    if (tid < RV * HID / 4)
        *(float4*)(sH + 4 * tid) = *(const float4*)(H + row0 * HID + 4 * tid);
    if (tid < RV) {  // fused logS: 8 partials per row
        float tot = 0.f;
        #pragma unroll
        for (int p = 0; p < 8; ++p) tot += P[(size_t)p * NROW + row0 + tid];
        sLogS[tid] = __logf(tot);
    }
    __syncthreads();

    const int v = vtile * VSK + 4 * tid;
    if (v >= VOCAB) return;  // tile-15 tail; no barriers below

    f32x2 wlo[HID], whi[HID];
    #pragma unroll
    for (int k = 0; k < HID; ++k) {
        f32x4 w4 = *(const f32x4*)(Wo + (size_t)k * VOCAB + v);
        wlo[k] = w4.xy; whi[k] = w4.zw;
    }
    const f32x4* sH4 = (const f32x4*)sH;
    const f32x4* sLS4 = (const f32x4*)sLogS;

    float* orow = out + (size_t)row0 * VOCAB + v;
    for (int r4 = 0; r4 < RV; r4 += 4) {
        f32x4 ls4 = sLS4[r4 >> 2];
        #pragma unroll
        for (int rr = 0; rr < 4; ++rr) {
            const int r = r4 + rr;
            f32x2 l01 = {0.f, 0.f}, l23 = {0.f, 0.f};
            #pragma unroll
            for (int q = 0; q < 4; ++q) {
                f32x4 hv = sH4[r * 4 + q];  // uniform addr b128 broadcast
                l01 += hv.x * wlo[4*q+0]; l23 += hv.x * whi[4*q+0];
                l01 += hv.y * wlo[4*q+1]; l23 += hv.y * whi[4*q+1];
                l01 += hv.z * wlo[4*q+2]; l23 += hv.z * whi[4*q+2];
                l01 += hv.w * wlo[4*q+3]; l23 += hv.w * whi[4*q+3];
            }
            const float ls = (rr == 0) ? ls4.x : (rr == 1) ? ls4.y
                           : (rr == 2) ? ls4.z : ls4.w;
            f32x4 o;
            o.xy = l01 - ls;
            o.zw = l23 - ls;
            __builtin_nontemporal_store(o, (f32x4*)orow);
            orow += VOCAB;
        }
    }
}

extern "C" void kernel_launch(void* const* d_in, const int* in_sizes, int n_in,
                              void* d_out, int out_size, void* d_ws, size_t ws_size,
                              hipStream_t stream) {
    const int*   idx    = (const int*)d_in[0];    // [SEQ, BATCH] int32
    const float* lookup = (const float*)d_in[1];  // [VOCAB, EMB]
    const float* Wx     = (const float*)d_in[2];  // [EMB, HID]
    const float* Wh     = (const float*)d_in[3];  // [HID, HID]
    const float* Wo     = (const float*)d_in[4];  // [HID, VOCAB]
    float* out = (float*)d_out;                   // [SEQ, BATCH, VOCAB]

    // ws layout: H (256 KB) | A = X@Wx (256 KB) | P partials 8x4096 (128 KB)
    float* Hbuf = (float*)d_ws;
    float* A    = Hbuf + NROW * HID;
    float* P    = A + NROW * HID;

    embed_xw<<<128, 512, 0, stream>>>(idx, lookup, Wx, A);
    rnn_recur<<<1, 512, 0, stream>>>(A, Wh, Hbuf);
    sum_exp_partial<<<512, 512, 0, stream>>>(Hbuf, Wo, P);
    write_logits<<<16 * (NROW / RV), 512, 0, stream>>>(Hbuf, Wo, P, out);
}

// Round 20
// 207.899 us; speedup vs baseline: 1.1320x; 1.1320x over previous
//
#include <hip/hip_runtime.h>

#define VOCAB 32000
#define EMB 32
#define HID 16
#define SEQ 128
#define BATCH 32
#define NROW (SEQ * BATCH)  // 4096 rows

typedef float f32x2 __attribute__((ext_vector_type(2)));
typedef float f32x4 __attribute__((ext_vector_type(4)));

// ---------------------------------------------------------------------------
// K0: A[t][b][j] = sum_e lookup[idx[t,b]][e] * Wx[e][j]  (no serial dep ->
// fully parallel; removes 2/3 of the serial step's FMA chain). 128 blocks.
// ---------------------------------------------------------------------------
__global__ __launch_bounds__(512) void embed_xw(
    const int* __restrict__ idx, const float* __restrict__ lookup,
    const float* __restrict__ Wx, float* __restrict__ A)
{
    __shared__ float sWx[EMB][HID];
    const int tid = threadIdx.x;
    ((float*)sWx)[tid] = Wx[tid];  // 512 == EMB*HID
    __syncthreads();

    const int g = blockIdx.x * 512 + tid;  // 0..65535
    const int row = g >> 4, j = g & 15;
    const float* xr = lookup + (size_t)idx[row] * EMB;  // 16 threads share row
    float a0 = 0.f, a1 = 0.f;
    #pragma unroll
    for (int e = 0; e < EMB; e += 2) {
        a0 += xr[e] * sWx[e][j];
        a1 += xr[e + 1] * sWx[e + 1][j];
    }
    A[g] = a0 + a1;
}

// ---------------------------------------------------------------------------
// K1: serial recurrence, A precomputed. One block, 512 thr = 32 b x 16 j.
// Wh column j in registers; per step: 4 ds_read_b128 (sH row) + 16 FMA +
// tanh-trick. Per-step deps stay in a 16-lane group -> no per-step barrier
// (same-wave DS ordering, validated rounds 1-19).
// ---------------------------------------------------------------------------
__global__ __launch_bounds__(512) void rnn_recur(
    const float* __restrict__ A, const float* __restrict__ Wh,
    float* __restrict__ Hout)
{
    __shared__ __align__(16) float sH[BATCH][HID];

    const int tid = threadIdx.x;
    const int b = tid >> 4, j = tid & 15;

    float wh[HID];
    #pragma unroll
    for (int k = 0; k < HID; ++k) wh[k] = Wh[k * HID + j];  // column j

    sH[b][j] = 1.0f;  // torch inits H to ones
    __syncthreads();

    float a0r = A[0 * 512 + tid];
    float a1r = A[1 * 512 + tid];
    float a2r = A[2 * 512 + tid];
    float a3r = A[3 * 512 + tid];

#define RNN_STEP(AR, T)                                                     \
    {                                                                       \
        float acc = AR;                                                     \
        if ((T) + 4 < SEQ) AR = A[((T) + 4) * 512 + tid];                   \
        const f32x4* sH4 = (const f32x4*)&sH[b][0];                         \
        f32x4 h0 = sH4[0], h1 = sH4[1], h2v = sH4[2], h3v = sH4[3];         \
        acc += h0.x * wh[0] + h0.y * wh[1] + h0.z * wh[2] + h0.w * wh[3];   \
        acc += h1.x * wh[4] + h1.y * wh[5] + h1.z * wh[6] + h1.w * wh[7];   \
        acc += h2v.x * wh[8] + h2v.y * wh[9] + h2v.z * wh[10]               \
             + h2v.w * wh[11];                                              \
        acc += h3v.x * wh[12] + h3v.y * wh[13] + h3v.z * wh[14]             \
             + h3v.w * wh[15];                                              \
        float e2 = __expf(2.f * acc);   /* tanh = 1 - 2/(e^{2a}+1) */       \
        float h = 1.f - 2.f / (e2 + 1.f);                                   \
        sH[b][j] = h;                                                       \
        Hout[(T) * 512 + tid] = h;                                          \
    }

    for (int t = 0; t < SEQ; t += 4) {
        RNN_STEP(a0r, t + 0)
        RNN_STEP(a1r, t + 1)
        RNN_STEP(a2r, t + 2)
        RNN_STEP(a3r, t + 3)
    }
#undef RNN_STEP
}

// ---------------------------------------------------------------------------
// K2: sum-of-exp, LANE = ROW layout (R14, measured 67us in R16; every
// deviation — occupancy, unroll, exp2, SMEM width, op_sel asm — regressed
// or nulled, R17-R19). Wave = 64 rows x 500-col slice. H per-lane in VGPRs;
// Wo wave-uniform -> s_load (SMEM); in-lane accumulation (no cross-lane
// reduce, no LDS staging, no tail). pk_fma: h-pair VGPR x Wo-pair SGPR.
// ---------------------------------------------------------------------------
#define CSL 500  // cols per wave slice

__global__ __launch_bounds__(512, 4) void sum_exp_partial(
    const float* __restrict__ H, const float* __restrict__ Wo,
    float* __restrict__ P)
{
    __shared__ float part[8][64];

    const int tid = threadIdx.x;
    const int lane = tid & 63;
    const int wave = tid >> 6;                    // 0..7
    const int rgrp = blockIdx.x >> 3;             // 0..63
    const int cchunk = blockIdx.x & 7;            // 0..7
    const int row0 = rgrp * 64;
    const int c0 = __builtin_amdgcn_readfirstlane(cchunk * 4000 + wave * CSL);

    f32x2 hp[HID];
    {
        const f32x4* h4 = (const f32x4*)(H + (size_t)(row0 + lane) * HID);
        #pragma unroll
        for (int q = 0; q < 4; ++q) {
            f32x4 hv = h4[q];
            hp[4 * q + 0] = f32x2{hv.x, hv.x};
            hp[4 * q + 1] = f32x2{hv.y, hv.y};
            hp[4 * q + 2] = f32x2{hv.z, hv.z};
            hp[4 * q + 3] = f32x2{hv.w, hv.w};
        }
    }

    const float* wbase = Wo + c0;
    float acc0 = 0.f, acc1 = 0.f, acc2 = 0.f, acc3 = 0.f;
    for (int v = 0; v < CSL; v += 4) {
        f32x2 a01 = {0.f, 0.f}, a23 = {0.f, 0.f};
        #pragma unroll
        for (int k = 0; k < HID; ++k) {
            f32x4 w4 = *(const f32x4*)(wbase + (size_t)k * VOCAB + v);
            asm("v_pk_fma_f32 %0, %1, %2, %0"
                : "+v"(a01) : "v"(hp[k]), "s"(w4.xy));
            asm("v_pk_fma_f32 %0, %1, %2, %0"
                : "+v"(a23) : "v"(hp[k]), "s"(w4.zw));
        }
        acc0 += __expf(a01.x); acc1 += __expf(a01.y);
        acc2 += __expf(a23.x); acc3 += __expf(a23.y);
    }

    part[wave][lane] = (acc0 + acc1) + (acc2 + acc3);
    __syncthreads();
    if (wave == 0) {
        float tot = 0.f;
        #pragma unroll
        for (int w = 0; w < 8; ++w) tot += part[w][lane];
        P[(size_t)cchunk * NROW + row0 + lane] = tot;
    }
}

// ---------------------------------------------------------------------------
// K3: output pass — R11-measured structure (107us = NT-store plateau: WRITE
// 1.0x, FETCH ~3MB, ~4.85 TB/s; plain stores, row-blocking, RV=32 all no
// better — R15/R18). LDS sH + plain FMA + NT float4 stores; logS fused
// from 8 partials. NT mandatory (R6: write-back RFO-thrash without it).
// ---------------------------------------------------------------------------
#define RV 64     // rows per block
#define VSK 2048  // vocab cols per block slice

__global__ __launch_bounds__(512, 4) void write_logits(
    const float* __restrict__ H, const float* __restrict__ Wo,
    const float* __restrict__ P, float* __restrict__ out)
{
    __shared__ __align__(16) float sH[RV * HID];  // 4 KB
    __shared__ __align__(16) float sLogS[RV];

    const int tid = threadIdx.x;
    const int vtile = blockIdx.x & 15;
    const int row0 = (blockIdx.x >> 4) * RV;

    if (tid < RV * HID / 4)
        *(float4*)(sH + 4 * tid) = *(const float4*)(H + row0 * HID + 4 * tid);
    if (tid < RV) {  // fused logS: 8 partials per row
        float tot = 0.f;
        #pragma unroll
        for (int p = 0; p < 8; ++p) tot += P[(size_t)p * NROW + row0 + tid];
        sLogS[tid] = __logf(tot);
    }
    __syncthreads();

    const int v = vtile * VSK + 4 * tid;
    if (v >= VOCAB) return;  // tile-15 tail; no barriers below

    f32x2 wlo[HID], whi[HID];
    #pragma unroll
    for (int k = 0; k < HID; ++k) {
        f32x4 w4 = *(const f32x4*)(Wo + (size_t)k * VOCAB + v);
        wlo[k] = w4.xy; whi[k] = w4.zw;
    }
    const f32x4* sH4 = (const f32x4*)sH;
    const f32x4* sLS4 = (const f32x4*)sLogS;

    float* orow = out + (size_t)row0 * VOCAB + v;
    for (int r4 = 0; r4 < RV; r4 += 4) {
        f32x4 ls4 = sLS4[r4 >> 2];  // one b128 broadcast per 4 rows
        #pragma unroll
        for (int rr = 0; rr < 4; ++rr) {
            const int r = r4 + rr;
            f32x2 l01 = {0.f, 0.f}, l23 = {0.f, 0.f};
            #pragma unroll
            for (int q = 0; q < 4; ++q) {
                f32x4 hv = sH4[r * 4 + q];  // uniform addr b128 broadcast
                l01 += hv.x * wlo[4*q+0]; l23 += hv.x * whi[4*q+0];
                l01 += hv.y * wlo[4*q+1]; l23 += hv.y * whi[4*q+1];
                l01 += hv.z * wlo[4*q+2]; l23 += hv.z * whi[4*q+2];
                l01 += hv.w * wlo[4*q+3]; l23 += hv.w * whi[4*q+3];
            }
            const float ls = (rr == 0) ? ls4.x : (rr == 1) ? ls4.y
                           : (rr == 2) ? ls4.z : ls4.w;
            f32x4 o;
            o.xy = l01 - ls;
            o.zw = l23 - ls;
            __builtin_nontemporal_store(o, (f32x4*)orow);
            orow += VOCAB;
        }
    }
}

extern "C" void kernel_launch(void* const* d_in, const int* in_sizes, int n_in,
                              void* d_out, int out_size, void* d_ws, size_t ws_size,
                              hipStream_t stream) {
    const int*   idx    = (const int*)d_in[0];    // [SEQ, BATCH] int32
    const float* lookup = (const float*)d_in[1];  // [VOCAB, EMB]
    const float* Wx     = (const float*)d_in[2];  // [EMB, HID]
    const float* Wh     = (const float*)d_in[3];  // [HID, HID]
    const float* Wo     = (const float*)d_in[4];  // [HID, VOCAB]
    float* out = (float*)d_out;                   // [SEQ, BATCH, VOCAB]

    // ws layout: H (256 KB) | A = X@Wx (256 KB) | P partials 8x4096 (128 KB)
    float* Hbuf = (float*)d_ws;
    float* A    = Hbuf + NROW * HID;
    float* P    = A + NROW * HID;

    embed_xw<<<128, 512, 0, stream>>>(idx, lookup, Wx, A);
    rnn_recur<<<1, 512, 0, stream>>>(A, Wh, Hbuf);
    sum_exp_partial<<<512, 512, 0, stream>>>(Hbuf, Wo, P);
    write_logits<<<16 * (NROW / RV), 512, 0, stream>>>(Hbuf, Wo, P, out);
}